// Round 6
// baseline (230.366 us; speedup 1.0000x reference)
//
#include <hip/hip_runtime.h>

// out = (I + W + ... + W^10) x == M . x  (M 256x256, exactly banded +-70).
// K1: build M per column; write split-precision bf16 hi/lo DIRECTLY in
//     per-(wave,chunk,lane) MFMA A-fragment layout (workspace 192 KB, inside
//     the proven envelope).
// K2: one 32-spatial tile per block (grid 3136).  R5 measured VGPR=32 under
//     __launch_bounds__(512,8): zero load batching, fully serialized per-chunk
//     L2+LDS latency chain (~38k cyc/block).  This version trades one block
//     of occupancy for ILP: (512,6) -> VGPR cap 84, 3 blocks/CU, explicit
//     double-buffered 3-chunk A-load groups (first group issued BEFORE the
//     barrier, each next group under the previous group's MFMAs), single
//     accumulator chain (-16 VGPR).

#define NCH 256
#define PAD 7
#define SCOPE 15
#define SPATIAL 3136
#define PER_B 802816          // 256*3136
#define STW 32                // spatial tile width
#define STILES_PER_B 98       // 3136/32
#define NTILES 3136           // 32*98 = one block per tile
#define MAXCH 12              // max K-chunks (of 16) per wave band window

typedef __attribute__((ext_vector_type(8))) __bf16 bf16x8;
typedef __attribute__((ext_vector_type(16))) float float16;
typedef __attribute__((ext_vector_type(4))) unsigned int uint4v;
typedef __attribute__((ext_vector_type(2))) unsigned int uint2v;

static __device__ __forceinline__ unsigned short f2bf_rn_u(float f) {
  unsigned u = __builtin_bit_cast(unsigned int, f);
  return (unsigned short)((u + 0x7FFFu + ((u >> 16) & 1u)) >> 16);
}
static __device__ __forceinline__ float bf2f_u(unsigned short h) {
  unsigned u = ((unsigned)h) << 16;
  return __builtin_bit_cast(float, u);
}
static __device__ __forceinline__ unsigned pack_bf2(float a, float b) {
  return (unsigned)f2bf_rn_u(a) | ((unsigned)f2bf_rn_u(b) << 16);
}
// split floats (a,b) -> hi packed word + lo (residual) packed word
static __device__ __forceinline__ void split2(float a, float b,
                                              unsigned& h, unsigned& l) {
  h = pack_bf2(a, b);
  const float ra = a - __builtin_bit_cast(float, h << 16);
  const float rb = b - __builtin_bit_cast(float, h & 0xFFFF0000u);
  l = pack_bf2(ra, rb);
}

// ---- Kernel 1: build M column d (block d); store fragment-layout hi/lo ----
// Fragment slot (w, i, lane) short j holds M[32w + (lane&31)]
// [(clo(w)+i)*16 + (lane>>5)*8 + j]; thread (d,c) owns element (c,d) and
// writes it to its unique slot. Slots with i >= nch(w) are never read.
__global__ void build_M_kernel(const float* __restrict__ w,
                               const int* __restrict__ max_steps_p,
                               unsigned short* __restrict__ AhF,
                               unsigned short* __restrict__ AlF) {
  const int d = blockIdx.x;
  const int c = threadIdx.x;
  __shared__ float v[2][NCH];
  __shared__ float wsh[SCOPE];
  if (c < SCOPE) wsh[c] = w[c];
  const float e = (c == d) ? 1.0f : 0.0f;
  v[0][c] = e;
  __syncthreads();
  const int steps = *max_steps_p;
  int cur = 0;
  for (int t = 0; t < steps; ++t) {
    float s = e;
#pragma unroll
    for (int j = 0; j < SCOPE; ++j) {
      const int cc = c + j - PAD;
      if (cc >= 0 && cc < NCH) s += wsh[j] * v[cur][cc];
    }
    cur ^= 1;
    v[cur][c] = s;
    __syncthreads();
  }
  const float f = v[cur][c];
  const unsigned short h = f2bf_rn_u(f);
  const unsigned short l = f2bf_rn_u(f - bf2f_u(h));

  const int wv = c >> 5;
  const int c0 = wv * 32;
  int clo = c0 - 70; if (clo < 0) clo = 0; clo >>= 4;
  int chi = c0 + 101; if (chi > 255) chi = 255; chi >>= 4;
  const int ch = d >> 4;
  if (ch >= clo && ch <= chi) {
    const int i    = ch - clo;
    const int half = (d >> 3) & 1;
    const int j    = d & 7;
    const int lane = half * 32 + (c & 31);
    const size_t dst = ((size_t)(wv * MAXCH + i) * 64 + lane) * 8 + j;
    AhF[dst] = h;
    AlF[dst] = l;
  }
}

// ---- Kernel 2 -------------------------------------------------------------
// 512 threads (8 waves); wave w -> output channels [32w,32w+32) of ONE tile.
// LDS XB: [k2 0..127][n 0..31][H,L] packed bf16-pair words,
// H word (k2,n) = (bf16(x[2k2][n]), bf16(x[2k2+1][n])), L = residual.

// load A-fragment pair for chunk i into named regs (predicate at use site)
#define LOADA(dh, dl, i)                                   \
  {                                                        \
    dh = *(const bf16x8*)(mhp + (i) * 512);                \
    dl = *(const bf16x8*)(mlp + (i) * 512);                \
  }
#define LOADA_P(dh, dl, i)                                 \
  if ((i) < nch) LOADA(dh, dl, i)

// consume chunk i: 4 ds_read_b64 + 3 MFMAs into the single acc chain
#define CHUNK(Ahr, Alr, i)                                              \
  {                                                                     \
    const int k2b = (clo + (i)) * 8 + half * 4;                         \
    const unsigned* bp = &XB[k2b * 64 + 2 * m];                         \
    const uint2v r0 = *(const uint2v*)(bp);                             \
    const uint2v r1 = *(const uint2v*)(bp + 64);                        \
    const uint2v r2 = *(const uint2v*)(bp + 128);                       \
    const uint2v r3 = *(const uint2v*)(bp + 192);                       \
    const uint4v hw = {r0.x, r1.x, r2.x, r3.x};                         \
    const uint4v lw = {r0.y, r1.y, r2.y, r3.y};                         \
    const bf16x8 bh = __builtin_bit_cast(bf16x8, hw);                   \
    const bf16x8 bl = __builtin_bit_cast(bf16x8, lw);                   \
    acc = __builtin_amdgcn_mfma_f32_32x32x16_bf16(Ahr, bh, acc, 0, 0, 0); \
    acc = __builtin_amdgcn_mfma_f32_32x32x16_bf16(Ahr, bl, acc, 0, 0, 0); \
    acc = __builtin_amdgcn_mfma_f32_32x32x16_bf16(Alr, bh, acc, 0, 0, 0); \
  }
#define CHUNK_P(Ahr, Alr, i)                               \
  if ((i) < nch) CHUNK(Ahr, Alr, i)

__global__ __launch_bounds__(512, 6) void apply_M_kernel(
    const float* __restrict__ x, const unsigned short* __restrict__ AhF,
    const unsigned short* __restrict__ AlF, float* __restrict__ out) {
  __shared__ unsigned XB[8192];  // 32 KB

  const int tid  = threadIdx.x;
  const int lane = tid & 63;
  const int w    = tid >> 6;
  const int m    = lane & 31;  // A row in c-tile == B spatial col
  const int half = lane >> 5;  // k-half
  const int c0   = w * 32;

  // exact nonzero band: rows [c0, c0+31] touch cols [c0-70, c0+101]
  int clo = c0 - 70; if (clo < 0) clo = 0; clo >>= 4;
  int chi = c0 + 101; if (chi > 255) chi = 255; chi >>= 4;
  const int nch = chi - clo + 1;  // 7..12 per wave (min is 7: chunks 0-6 safe)

  // loader geometry: thread -> (d-pair rows dg, dg+64; 4 spatial cols sq..sq+3)
  const int sq = (tid & 7) * 4;
  const int dg = tid >> 3;  // 0..63

  const int tau = blockIdx.x;
  const float* gb = x + (size_t)(tau / STILES_PER_B) * PER_B
                      + (size_t)(tau % STILES_PER_B) * STW;
  const float4 g0 = *(const float4*)(gb + (size_t)(2 * dg) * SPATIAL + sq);
  const float4 g1 = *(const float4*)(gb + (size_t)(2 * dg + 1) * SPATIAL + sq);
  const float4 g2 = *(const float4*)(gb + (size_t)(2 * dg + 128) * SPATIAL + sq);
  const float4 g3 = *(const float4*)(gb + (size_t)(2 * dg + 129) * SPATIAL + sq);

  // A-fragment base for this (wave, lane); chunk i at +i*512 shorts.
  // Coalesced (lane-consecutive 16B), L2-hot (shared by all 3136 blocks).
  const unsigned short* mhp = AhF + ((size_t)(w * MAXCH) * 64 + lane) * 8;
  const unsigned short* mlp = AlF + ((size_t)(w * MAXCH) * 64 + lane) * 8;

  // group P: chunks 0-2 issued NOW -> L2 latency overlaps split + barrier
  bf16x8 pH0, pL0, pH1, pL1, pH2, pL2;
  bf16x8 qH0, qL0, qH1, qL1, qH2, qL2;
  LOADA(pH0, pL0, 0) LOADA(pH1, pL1, 1) LOADA(pH2, pL2, 2)

  // cooperative split: registers -> interleaved (H,L) words in LDS
  {
    unsigned h0, h1, h2, h3, l0, l1, l2, l3;
    split2(g0.x, g1.x, h0, l0); split2(g0.y, g1.y, h1, l1);
    split2(g0.z, g1.z, h2, l2); split2(g0.w, g1.w, h3, l3);
    unsigned* p = &XB[dg * 64 + sq * 2];
    *(uint4v*)(p)     = (uint4v){h0, l0, h1, l1};
    *(uint4v*)(p + 4) = (uint4v){h2, l2, h3, l3};
    split2(g2.x, g3.x, h0, l0); split2(g2.y, g3.y, h1, l1);
    split2(g2.z, g3.z, h2, l2); split2(g2.w, g3.w, h3, l3);
    unsigned* q = &XB[(dg + 64) * 64 + sq * 2];
    *(uint4v*)(q)     = (uint4v){h0, l0, h1, l1};
    *(uint4v*)(q + 4) = (uint4v){h2, l2, h3, l3};
  }

  // LDS writes visible to all waves; A prefetch loads NOT drained (raw
  // barrier, no vmcnt(0)) — proven pattern from R2
  asm volatile("s_waitcnt lgkmcnt(0)" ::: "memory");
  __builtin_amdgcn_s_barrier();

  float16 acc;
#pragma unroll
  for (int q = 0; q < 16; ++q) acc[q] = 0.0f;

  // software pipeline: group g+1 loads fly under group g's LDS reads + MFMAs
  LOADA(qH0, qL0, 3) LOADA(qH1, qL1, 4) LOADA(qH2, qL2, 5)
  CHUNK(pH0, pL0, 0) CHUNK(pH1, pL1, 1) CHUNK(pH2, pL2, 2)

  LOADA(pH0, pL0, 6) LOADA_P(pH1, pL1, 7) LOADA_P(pH2, pL2, 8)
  CHUNK(qH0, qL0, 3) CHUNK(qH1, qL1, 4) CHUNK(qH2, qL2, 5)

  LOADA_P(qH0, qL0, 9) LOADA_P(qH1, qL1, 10) LOADA_P(qH2, qL2, 11)
  CHUNK(pH0, pL0, 6) CHUNK_P(pH1, pL1, 7) CHUNK_P(pH2, pL2, 8)

  CHUNK_P(qH0, qL0, 9) CHUNK_P(qH1, qL1, 10) CHUNK_P(qH2, qL2, 11)

  // epilogue: C/D map (32x32): col = lane&31, row = (r&3)+8*(r>>2)+4*half
  const int b  = tau / STILES_PER_B;
  const int s0 = (tau % STILES_PER_B) * STW;
  float* ob = out + (size_t)b * PER_B + (size_t)s0 + m;
#pragma unroll
  for (int r = 0; r < 16; ++r) {
    const int row = (r & 3) + 8 * (r >> 2) + 4 * half;
    ob[(size_t)(c0 + row) * SPATIAL] = acc[r];
  }
}

extern "C" void kernel_launch(void* const* d_in, const int* in_sizes, int n_in,
                              void* d_out, int out_size, void* d_ws, size_t ws_size,
                              hipStream_t stream) {
  const float* x = (const float*)d_in[0];  // (32, 256, 56, 56) fp32
  const float* w = (const float*)d_in[1];  // (15,) fp32
  const int* ms = (const int*)d_in[2];     // scalar int (10)
  float* out = (float*)d_out;              // (32, 256, 56, 56) fp32

  // workspace: 2 x 96 KB fragment buffers = 192 KB total (< 256 KB proven)
  unsigned short* AhF = (unsigned short*)d_ws;       // 8*12*64*8*2B = 96 KB
  unsigned short* AlF = AhF + 8 * MAXCH * 64 * 8;    // 96 KB

  build_M_kernel<<<NCH, NCH, 0, stream>>>(w, ms, AhF, AlF);
  apply_M_kernel<<<NTILES, 512, 0, stream>>>(x, AhF, AlF, out);
}

// Round 7
// 205.556 us; speedup vs baseline: 1.1207x; 1.1207x over previous
//
#include <hip/hip_runtime.h>

// out = (I + W + ... + W^10) x == M . x  (M 256x256, exactly banded +-70).
// K1: build M per column; write split-precision bf16 hi/lo DIRECTLY in
//     per-(wave,chunk,lane) MFMA A-fragment layout (workspace 192 KB).
// K2: W=64 spatial tile per block (grid 1568).  vs R5/R6 (W=32):
//     - each A-chunk amortized over TWO n-half MFMAs (A L2-latency per
//       output halved; 6 MFMA + 8 ds_read per chunk)
//     - x loads and out stores are 256 B contiguous runs (R6 showed 128 B
//       runs caused partial-line write blowup: WRITE 100->159 MB)
//     - (512,4): VGPR cap 128 (LDS 64 KB caps at 2 blocks/CU anyway) ->
//       headroom for a REAL 2-group A pipeline
//     - load groups pinned with __builtin_amdgcn_sched_barrier(0) (R6
//       proved the scheduler sinks unpinned loads: VGPR stayed 40)

#define NCH 256
#define PAD 7
#define SCOPE 15
#define SPATIAL 3136
#define PER_B 802816          // 256*3136
#define STW 64                // spatial tile width
#define STILES_PER_B 49       // 3136/64
#define NTILES 1568           // 32*49 = one block per tile
#define MAXCH 12              // max K-chunks (of 16) per wave band window

typedef __attribute__((ext_vector_type(8))) __bf16 bf16x8;
typedef __attribute__((ext_vector_type(16))) float float16;
typedef __attribute__((ext_vector_type(4))) unsigned int uint4v;
typedef __attribute__((ext_vector_type(2))) unsigned int uint2v;

static __device__ __forceinline__ unsigned short f2bf_rn_u(float f) {
  unsigned u = __builtin_bit_cast(unsigned int, f);
  return (unsigned short)((u + 0x7FFFu + ((u >> 16) & 1u)) >> 16);
}
static __device__ __forceinline__ float bf2f_u(unsigned short h) {
  unsigned u = ((unsigned)h) << 16;
  return __builtin_bit_cast(float, u);
}
static __device__ __forceinline__ unsigned pack_bf2(float a, float b) {
  return (unsigned)f2bf_rn_u(a) | ((unsigned)f2bf_rn_u(b) << 16);
}
// split floats (a,b) -> hi packed word + lo (residual) packed word
static __device__ __forceinline__ void split2(float a, float b,
                                              unsigned& h, unsigned& l) {
  h = pack_bf2(a, b);
  const float ra = a - __builtin_bit_cast(float, h << 16);
  const float rb = b - __builtin_bit_cast(float, h & 0xFFFF0000u);
  l = pack_bf2(ra, rb);
}

// ---- Kernel 1: build M column d (block d); store fragment-layout hi/lo ----
// Fragment slot (w, i, lane) short j holds M[32w + (lane&31)]
// [(clo(w)+i)*16 + (lane>>5)*8 + j]; thread (d,c) owns element (c,d) and
// writes it to its unique slot. Slots with i >= nch(w) are never read.
__global__ void build_M_kernel(const float* __restrict__ w,
                               const int* __restrict__ max_steps_p,
                               unsigned short* __restrict__ AhF,
                               unsigned short* __restrict__ AlF) {
  const int d = blockIdx.x;
  const int c = threadIdx.x;
  __shared__ float v[2][NCH];
  __shared__ float wsh[SCOPE];
  if (c < SCOPE) wsh[c] = w[c];
  const float e = (c == d) ? 1.0f : 0.0f;
  v[0][c] = e;
  __syncthreads();
  const int steps = *max_steps_p;
  int cur = 0;
  for (int t = 0; t < steps; ++t) {
    float s = e;
#pragma unroll
    for (int j = 0; j < SCOPE; ++j) {
      const int cc = c + j - PAD;
      if (cc >= 0 && cc < NCH) s += wsh[j] * v[cur][cc];
    }
    cur ^= 1;
    v[cur][c] = s;
    __syncthreads();
  }
  const float f = v[cur][c];
  const unsigned short h = f2bf_rn_u(f);
  const unsigned short l = f2bf_rn_u(f - bf2f_u(h));

  const int wv = c >> 5;
  const int c0 = wv * 32;
  int clo = c0 - 70; if (clo < 0) clo = 0; clo >>= 4;
  int chi = c0 + 101; if (chi > 255) chi = 255; chi >>= 4;
  const int ch = d >> 4;
  if (ch >= clo && ch <= chi) {
    const int i    = ch - clo;
    const int half = (d >> 3) & 1;
    const int j    = d & 7;
    const int lane = half * 32 + (c & 31);
    const size_t dst = ((size_t)(wv * MAXCH + i) * 64 + lane) * 8 + j;
    AhF[dst] = h;
    AlF[dst] = l;
  }
}

// ---- Kernel 2 -------------------------------------------------------------
// 512 threads (8 waves); wave w -> output channels [32w,32w+32) of ONE
// W=64 tile.  LDS XB: [k2 0..127][col 0..63][H,L] packed bf16-pair words,
// H word (k2,n) = (bf16(x[2k2][n]), bf16(x[2k2+1][n])), L = residual.

#define LOADA(dh, dl, i)                                   \
  {                                                        \
    dh = *(const bf16x8*)(mhp + (i) * 512);                \
    dl = *(const bf16x8*)(mlp + (i) * 512);                \
  }

// consume chunk i for BOTH n-halves: 8 ds_read_b64 + 6 MFMAs
#define CHUNK(Ahr, Alr, i)                                                \
  {                                                                       \
    const int k2b = (clo + (i)) * 8 + half * 4;                           \
    const unsigned* bp = &XB[k2b * 128 + 2 * m];                          \
    const uint2v r0 = *(const uint2v*)(bp);                               \
    const uint2v r1 = *(const uint2v*)(bp + 128);                         \
    const uint2v r2 = *(const uint2v*)(bp + 256);                         \
    const uint2v r3 = *(const uint2v*)(bp + 384);                         \
    const unsigned* bq = bp + 64;                                         \
    const uint2v s0v = *(const uint2v*)(bq);                              \
    const uint2v s1v = *(const uint2v*)(bq + 128);                        \
    const uint2v s2v = *(const uint2v*)(bq + 256);                        \
    const uint2v s3v = *(const uint2v*)(bq + 384);                        \
    const bf16x8 bh0 = __builtin_bit_cast(bf16x8,                         \
        (uint4v){r0.x, r1.x, r2.x, r3.x});                                \
    const bf16x8 bl0 = __builtin_bit_cast(bf16x8,                         \
        (uint4v){r0.y, r1.y, r2.y, r3.y});                                \
    const bf16x8 bh1 = __builtin_bit_cast(bf16x8,                         \
        (uint4v){s0v.x, s1v.x, s2v.x, s3v.x});                            \
    const bf16x8 bl1 = __builtin_bit_cast(bf16x8,                         \
        (uint4v){s0v.y, s1v.y, s2v.y, s3v.y});                            \
    acc0 = __builtin_amdgcn_mfma_f32_32x32x16_bf16(Ahr, bh0, acc0, 0, 0, 0); \
    acc1 = __builtin_amdgcn_mfma_f32_32x32x16_bf16(Ahr, bh1, acc1, 0, 0, 0); \
    acc0 = __builtin_amdgcn_mfma_f32_32x32x16_bf16(Ahr, bl0, acc0, 0, 0, 0); \
    acc1 = __builtin_amdgcn_mfma_f32_32x32x16_bf16(Ahr, bl1, acc1, 0, 0, 0); \
    acc0 = __builtin_amdgcn_mfma_f32_32x32x16_bf16(Alr, bh0, acc0, 0, 0, 0); \
    acc1 = __builtin_amdgcn_mfma_f32_32x32x16_bf16(Alr, bh1, acc1, 0, 0, 0); \
  }
#define CHUNK_P(Ahr, Alr, i)                               \
  if ((i) < nch) CHUNK(Ahr, Alr, i)

__global__ __launch_bounds__(512, 4) void apply_M_kernel(
    const float* __restrict__ x, const unsigned short* __restrict__ AhF,
    const unsigned short* __restrict__ AlF, float* __restrict__ out) {
  __shared__ unsigned XB[16384];  // 64 KB

  const int tid  = threadIdx.x;
  const int lane = tid & 63;
  const int w    = tid >> 6;
  const int m    = lane & 31;  // A row in c-tile == B spatial col (n-half 0)
  const int half = lane >> 5;  // k-half
  const int c0   = w * 32;

  // exact nonzero band: rows [c0, c0+31] touch cols [c0-70, c0+101]
  int clo = c0 - 70; if (clo < 0) clo = 0; clo >>= 4;
  int chi = c0 + 101; if (chi > 255) chi = 255; chi >>= 4;
  const int nch = chi - clo + 1;  // 7..12 per wave (chunks 0-6 always valid)

  // loader geometry: thread -> k2 rows {dg, dg+32, dg+64, dg+96},
  // each a channel pair (2k2, 2k2+1); 4 spatial cols sq..sq+3
  const int sq = (tid & 15) * 4;
  const int dg = tid >> 4;  // 0..31

  const int tau = blockIdx.x;
  const float* gb = x + (size_t)(tau / STILES_PER_B) * PER_B
                      + (size_t)(tau % STILES_PER_B) * STW;
  const float4 g0 = *(const float4*)(gb + (size_t)(2 * dg) * SPATIAL + sq);
  const float4 g1 = *(const float4*)(gb + (size_t)(2 * dg + 1) * SPATIAL + sq);
  const float4 g2 = *(const float4*)(gb + (size_t)(2 * dg + 64) * SPATIAL + sq);
  const float4 g3 = *(const float4*)(gb + (size_t)(2 * dg + 65) * SPATIAL + sq);
  const float4 g4 = *(const float4*)(gb + (size_t)(2 * dg + 128) * SPATIAL + sq);
  const float4 g5 = *(const float4*)(gb + (size_t)(2 * dg + 129) * SPATIAL + sq);
  const float4 g6 = *(const float4*)(gb + (size_t)(2 * dg + 192) * SPATIAL + sq);
  const float4 g7 = *(const float4*)(gb + (size_t)(2 * dg + 193) * SPATIAL + sq);

  // A-fragment base for this (wave, lane); chunk i at +i*512 shorts.
  const unsigned short* mhp = AhF + ((size_t)(w * MAXCH) * 64 + lane) * 8;
  const unsigned short* mlp = AlF + ((size_t)(w * MAXCH) * 64 + lane) * 8;

  // group P (chunks 0-2) issued NOW; sched_barrier pins issue before the
  // split/barrier so L2 latency hides there (R6: unpinned loads get sunk)
  bf16x8 pH0, pL0, pH1, pL1, pH2, pL2;
  bf16x8 qH0, qL0, qH1, qL1, qH2, qL2;
  LOADA(pH0, pL0, 0) LOADA(pH1, pL1, 1) LOADA(pH2, pL2, 2)
  __builtin_amdgcn_sched_barrier(0);

  // cooperative split: registers -> interleaved (H,L) words in LDS
  {
    unsigned h0, h1, h2, h3, l0, l1, l2, l3;
    split2(g0.x, g1.x, h0, l0); split2(g0.y, g1.y, h1, l1);
    split2(g0.z, g1.z, h2, l2); split2(g0.w, g1.w, h3, l3);
    unsigned* p = &XB[dg * 128 + sq * 2];
    *(uint4v*)(p)     = (uint4v){h0, l0, h1, l1};
    *(uint4v*)(p + 4) = (uint4v){h2, l2, h3, l3};
    split2(g2.x, g3.x, h0, l0); split2(g2.y, g3.y, h1, l1);
    split2(g2.z, g3.z, h2, l2); split2(g2.w, g3.w, h3, l3);
    p = &XB[(dg + 32) * 128 + sq * 2];
    *(uint4v*)(p)     = (uint4v){h0, l0, h1, l1};
    *(uint4v*)(p + 4) = (uint4v){h2, l2, h3, l3};
    split2(g4.x, g5.x, h0, l0); split2(g4.y, g5.y, h1, l1);
    split2(g4.z, g5.z, h2, l2); split2(g4.w, g5.w, h3, l3);
    p = &XB[(dg + 64) * 128 + sq * 2];
    *(uint4v*)(p)     = (uint4v){h0, l0, h1, l1};
    *(uint4v*)(p + 4) = (uint4v){h2, l2, h3, l3};
    split2(g6.x, g7.x, h0, l0); split2(g6.y, g7.y, h1, l1);
    split2(g6.z, g7.z, h2, l2); split2(g6.w, g7.w, h3, l3);
    p = &XB[(dg + 96) * 128 + sq * 2];
    *(uint4v*)(p)     = (uint4v){h0, l0, h1, l1};
    *(uint4v*)(p + 4) = (uint4v){h2, l2, h3, l3};
  }

  // LDS writes visible to all waves; in-flight A loads NOT drained
  asm volatile("s_waitcnt lgkmcnt(0)" ::: "memory");
  __builtin_amdgcn_s_barrier();

  float16 acc0, acc1;
#pragma unroll
  for (int q = 0; q < 16; ++q) { acc0[q] = 0.0f; acc1[q] = 0.0f; }

  // software pipeline; every load group pinned with sched_barrier(0).
  // A loads are always in-bounds (buffer holds MAXCH slots); only the
  // MFMAs are predicated, so garbage never enters the accumulators.
  LOADA(qH0, qL0, 3) LOADA(qH1, qL1, 4) LOADA(qH2, qL2, 5)
  __builtin_amdgcn_sched_barrier(0);
  CHUNK(pH0, pL0, 0) CHUNK(pH1, pL1, 1) CHUNK(pH2, pL2, 2)

  LOADA(pH0, pL0, 6) LOADA(pH1, pL1, 7) LOADA(pH2, pL2, 8)
  __builtin_amdgcn_sched_barrier(0);
  CHUNK(qH0, qL0, 3) CHUNK(qH1, qL1, 4) CHUNK(qH2, qL2, 5)

  LOADA(qH0, qL0, 9) LOADA(qH1, qL1, 10) LOADA(qH2, qL2, 11)
  __builtin_amdgcn_sched_barrier(0);
  CHUNK(pH0, pL0, 6) CHUNK_P(pH1, pL1, 7) CHUNK_P(pH2, pL2, 8)

  CHUNK_P(qH0, qL0, 9) CHUNK_P(qH1, qL1, 10) CHUNK_P(qH2, qL2, 11)

  // epilogue: C/D map (32x32): col = lane&31, row = (r&3)+8*(r>>2)+4*half;
  // acc0 -> cols s0+m, acc1 -> cols s0+32+m (256 B run per row per wave)
  const int b  = tau / STILES_PER_B;
  const int s0 = (tau % STILES_PER_B) * STW;
  float* ob = out + (size_t)b * PER_B + (size_t)s0 + m;
#pragma unroll
  for (int r = 0; r < 16; ++r) {
    const int row = (r & 3) + 8 * (r >> 2) + 4 * half;
    float* orow = ob + (size_t)(c0 + row) * SPATIAL;
    orow[0]  = acc0[r];
    orow[32] = acc1[r];
  }
}

extern "C" void kernel_launch(void* const* d_in, const int* in_sizes, int n_in,
                              void* d_out, int out_size, void* d_ws, size_t ws_size,
                              hipStream_t stream) {
  const float* x = (const float*)d_in[0];  // (32, 256, 56, 56) fp32
  const float* w = (const float*)d_in[1];  // (15,) fp32
  const int* ms = (const int*)d_in[2];     // scalar int (10)
  float* out = (float*)d_out;              // (32, 256, 56, 56) fp32

  // workspace: 2 x 96 KB fragment buffers = 192 KB total (< 256 KB proven)
  unsigned short* AhF = (unsigned short*)d_ws;       // 8*12*64*8*2B = 96 KB
  unsigned short* AlF = AhF + 8 * MAXCH * 64 * 8;    // 96 KB

  build_M_kernel<<<NCH, NCH, 0, stream>>>(w, ms, AhF, AlF);
  apply_M_kernel<<<NTILES, 512, 0, stream>>>(x, AhF, AlF, out);
}

// Round 8
// 201.357 us; speedup vs baseline: 1.1441x; 1.0209x over previous
//
#include <hip/hip_runtime.h>

// out = (I + W + ... + W^10) x == M . x  (M 256x256, exactly banded +-70).
// K1: build M per column; write split-precision bf16 hi/lo DIRECTLY in
//     per-(wave,chunk,lane) MFMA A-fragment layout (workspace 192 KB).
// K2: W=64 spatial tile per block (grid 1568), R7 structure UNCHANGED except
//     the output stores are NON-TEMPORAL.  Cross-round evidence (R0/R5/R7
//     all ~74-78 us apply with radically different structures; duration ==
//     traffic / ~2.2 TB/s in every BW-saturating round) says we sit on an
//     effective-BW wall, not a latency/structure wall.  NT stores:
//     (1) out (103 MB) stops flowing through L3 -> x (103 MB) becomes fully
//         L3-resident across bench iterations (FETCH_SIZE ~51 MB -> ~0)
//     (2) HBM bus becomes a near-pure write stream (no R/W turnaround mix)

#define NCH 256
#define PAD 7
#define SCOPE 15
#define SPATIAL 3136
#define PER_B 802816          // 256*3136
#define STW 64                // spatial tile width
#define STILES_PER_B 49       // 3136/64
#define NTILES 1568           // 32*49 = one block per tile
#define MAXCH 12              // max K-chunks (of 16) per wave band window

typedef __attribute__((ext_vector_type(8))) __bf16 bf16x8;
typedef __attribute__((ext_vector_type(16))) float float16;
typedef __attribute__((ext_vector_type(4))) unsigned int uint4v;
typedef __attribute__((ext_vector_type(2))) unsigned int uint2v;

static __device__ __forceinline__ unsigned short f2bf_rn_u(float f) {
  unsigned u = __builtin_bit_cast(unsigned int, f);
  return (unsigned short)((u + 0x7FFFu + ((u >> 16) & 1u)) >> 16);
}
static __device__ __forceinline__ float bf2f_u(unsigned short h) {
  unsigned u = ((unsigned)h) << 16;
  return __builtin_bit_cast(float, u);
}
static __device__ __forceinline__ unsigned pack_bf2(float a, float b) {
  return (unsigned)f2bf_rn_u(a) | ((unsigned)f2bf_rn_u(b) << 16);
}
// split floats (a,b) -> hi packed word + lo (residual) packed word
static __device__ __forceinline__ void split2(float a, float b,
                                              unsigned& h, unsigned& l) {
  h = pack_bf2(a, b);
  const float ra = a - __builtin_bit_cast(float, h << 16);
  const float rb = b - __builtin_bit_cast(float, h & 0xFFFF0000u);
  l = pack_bf2(ra, rb);
}

// ---- Kernel 1: build M column d (block d); store fragment-layout hi/lo ----
// Fragment slot (w, i, lane) short j holds M[32w + (lane&31)]
// [(clo(w)+i)*16 + (lane>>5)*8 + j]; thread (d,c) owns element (c,d) and
// writes it to its unique slot. Slots with i >= nch(w) are never read.
__global__ void build_M_kernel(const float* __restrict__ w,
                               const int* __restrict__ max_steps_p,
                               unsigned short* __restrict__ AhF,
                               unsigned short* __restrict__ AlF) {
  const int d = blockIdx.x;
  const int c = threadIdx.x;
  __shared__ float v[2][NCH];
  __shared__ float wsh[SCOPE];
  if (c < SCOPE) wsh[c] = w[c];
  const float e = (c == d) ? 1.0f : 0.0f;
  v[0][c] = e;
  __syncthreads();
  const int steps = *max_steps_p;
  int cur = 0;
  for (int t = 0; t < steps; ++t) {
    float s = e;
#pragma unroll
    for (int j = 0; j < SCOPE; ++j) {
      const int cc = c + j - PAD;
      if (cc >= 0 && cc < NCH) s += wsh[j] * v[cur][cc];
    }
    cur ^= 1;
    v[cur][c] = s;
    __syncthreads();
  }
  const float f = v[cur][c];
  const unsigned short h = f2bf_rn_u(f);
  const unsigned short l = f2bf_rn_u(f - bf2f_u(h));

  const int wv = c >> 5;
  const int c0 = wv * 32;
  int clo = c0 - 70; if (clo < 0) clo = 0; clo >>= 4;
  int chi = c0 + 101; if (chi > 255) chi = 255; chi >>= 4;
  const int ch = d >> 4;
  if (ch >= clo && ch <= chi) {
    const int i    = ch - clo;
    const int half = (d >> 3) & 1;
    const int j    = d & 7;
    const int lane = half * 32 + (c & 31);
    const size_t dst = ((size_t)(wv * MAXCH + i) * 64 + lane) * 8 + j;
    AhF[dst] = h;
    AlF[dst] = l;
  }
}

// ---- Kernel 2 -------------------------------------------------------------
// 512 threads (8 waves); wave w -> output channels [32w,32w+32) of ONE
// W=64 tile.  LDS XB: [k2 0..127][col 0..63][H,L] packed bf16-pair words,
// H word (k2,n) = (bf16(x[2k2][n]), bf16(x[2k2+1][n])), L = residual.

#define LOADA(dh, dl, i)                                   \
  {                                                        \
    dh = *(const bf16x8*)(mhp + (i) * 512);                \
    dl = *(const bf16x8*)(mlp + (i) * 512);                \
  }

// consume chunk i for BOTH n-halves: 8 ds_read_b64 + 6 MFMAs
#define CHUNK(Ahr, Alr, i)                                                \
  {                                                                       \
    const int k2b = (clo + (i)) * 8 + half * 4;                           \
    const unsigned* bp = &XB[k2b * 128 + 2 * m];                          \
    const uint2v r0 = *(const uint2v*)(bp);                               \
    const uint2v r1 = *(const uint2v*)(bp + 128);                         \
    const uint2v r2 = *(const uint2v*)(bp + 256);                         \
    const uint2v r3 = *(const uint2v*)(bp + 384);                         \
    const unsigned* bq = bp + 64;                                         \
    const uint2v s0v = *(const uint2v*)(bq);                              \
    const uint2v s1v = *(const uint2v*)(bq + 128);                        \
    const uint2v s2v = *(const uint2v*)(bq + 256);                        \
    const uint2v s3v = *(const uint2v*)(bq + 384);                        \
    const bf16x8 bh0 = __builtin_bit_cast(bf16x8,                         \
        (uint4v){r0.x, r1.x, r2.x, r3.x});                                \
    const bf16x8 bl0 = __builtin_bit_cast(bf16x8,                         \
        (uint4v){r0.y, r1.y, r2.y, r3.y});                                \
    const bf16x8 bh1 = __builtin_bit_cast(bf16x8,                         \
        (uint4v){s0v.x, s1v.x, s2v.x, s3v.x});                            \
    const bf16x8 bl1 = __builtin_bit_cast(bf16x8,                         \
        (uint4v){s0v.y, s1v.y, s2v.y, s3v.y});                            \
    acc0 = __builtin_amdgcn_mfma_f32_32x32x16_bf16(Ahr, bh0, acc0, 0, 0, 0); \
    acc1 = __builtin_amdgcn_mfma_f32_32x32x16_bf16(Ahr, bh1, acc1, 0, 0, 0); \
    acc0 = __builtin_amdgcn_mfma_f32_32x32x16_bf16(Ahr, bl0, acc0, 0, 0, 0); \
    acc1 = __builtin_amdgcn_mfma_f32_32x32x16_bf16(Ahr, bl1, acc1, 0, 0, 0); \
    acc0 = __builtin_amdgcn_mfma_f32_32x32x16_bf16(Alr, bh0, acc0, 0, 0, 0); \
    acc1 = __builtin_amdgcn_mfma_f32_32x32x16_bf16(Alr, bh1, acc1, 0, 0, 0); \
  }
#define CHUNK_P(Ahr, Alr, i)                               \
  if ((i) < nch) CHUNK(Ahr, Alr, i)

__global__ __launch_bounds__(512, 4) void apply_M_kernel(
    const float* __restrict__ x, const unsigned short* __restrict__ AhF,
    const unsigned short* __restrict__ AlF, float* __restrict__ out) {
  __shared__ unsigned XB[16384];  // 64 KB

  const int tid  = threadIdx.x;
  const int lane = tid & 63;
  const int w    = tid >> 6;
  const int m    = lane & 31;  // A row in c-tile == B spatial col (n-half 0)
  const int half = lane >> 5;  // k-half
  const int c0   = w * 32;

  // exact nonzero band: rows [c0, c0+31] touch cols [c0-70, c0+101]
  int clo = c0 - 70; if (clo < 0) clo = 0; clo >>= 4;
  int chi = c0 + 101; if (chi > 255) chi = 255; chi >>= 4;
  const int nch = chi - clo + 1;  // 7..12 per wave (chunks 0-6 always valid)

  // loader geometry: thread -> k2 rows {dg, dg+32, dg+64, dg+96},
  // each a channel pair (2k2, 2k2+1); 4 spatial cols sq..sq+3
  const int sq = (tid & 15) * 4;
  const int dg = tid >> 4;  // 0..31

  const int tau = blockIdx.x;
  const float* gb = x + (size_t)(tau / STILES_PER_B) * PER_B
                      + (size_t)(tau % STILES_PER_B) * STW;
  const float4 g0 = *(const float4*)(gb + (size_t)(2 * dg) * SPATIAL + sq);
  const float4 g1 = *(const float4*)(gb + (size_t)(2 * dg + 1) * SPATIAL + sq);
  const float4 g2 = *(const float4*)(gb + (size_t)(2 * dg + 64) * SPATIAL + sq);
  const float4 g3 = *(const float4*)(gb + (size_t)(2 * dg + 65) * SPATIAL + sq);
  const float4 g4 = *(const float4*)(gb + (size_t)(2 * dg + 128) * SPATIAL + sq);
  const float4 g5 = *(const float4*)(gb + (size_t)(2 * dg + 129) * SPATIAL + sq);
  const float4 g6 = *(const float4*)(gb + (size_t)(2 * dg + 192) * SPATIAL + sq);
  const float4 g7 = *(const float4*)(gb + (size_t)(2 * dg + 193) * SPATIAL + sq);

  // A-fragment base for this (wave, lane); chunk i at +i*512 shorts.
  const unsigned short* mhp = AhF + ((size_t)(w * MAXCH) * 64 + lane) * 8;
  const unsigned short* mlp = AlF + ((size_t)(w * MAXCH) * 64 + lane) * 8;

  // group P (chunks 0-2) issued NOW; sched_barrier pins issue before the
  // split/barrier so L2 latency hides there (R6: unpinned loads get sunk)
  bf16x8 pH0, pL0, pH1, pL1, pH2, pL2;
  bf16x8 qH0, qL0, qH1, qL1, qH2, qL2;
  LOADA(pH0, pL0, 0) LOADA(pH1, pL1, 1) LOADA(pH2, pL2, 2)
  __builtin_amdgcn_sched_barrier(0);

  // cooperative split: registers -> interleaved (H,L) words in LDS
  {
    unsigned h0, h1, h2, h3, l0, l1, l2, l3;
    split2(g0.x, g1.x, h0, l0); split2(g0.y, g1.y, h1, l1);
    split2(g0.z, g1.z, h2, l2); split2(g0.w, g1.w, h3, l3);
    unsigned* p = &XB[dg * 128 + sq * 2];
    *(uint4v*)(p)     = (uint4v){h0, l0, h1, l1};
    *(uint4v*)(p + 4) = (uint4v){h2, l2, h3, l3};
    split2(g2.x, g3.x, h0, l0); split2(g2.y, g3.y, h1, l1);
    split2(g2.z, g3.z, h2, l2); split2(g2.w, g3.w, h3, l3);
    p = &XB[(dg + 32) * 128 + sq * 2];
    *(uint4v*)(p)     = (uint4v){h0, l0, h1, l1};
    *(uint4v*)(p + 4) = (uint4v){h2, l2, h3, l3};
    split2(g4.x, g5.x, h0, l0); split2(g4.y, g5.y, h1, l1);
    split2(g4.z, g5.z, h2, l2); split2(g4.w, g5.w, h3, l3);
    p = &XB[(dg + 64) * 128 + sq * 2];
    *(uint4v*)(p)     = (uint4v){h0, l0, h1, l1};
    *(uint4v*)(p + 4) = (uint4v){h2, l2, h3, l3};
    split2(g6.x, g7.x, h0, l0); split2(g6.y, g7.y, h1, l1);
    split2(g6.z, g7.z, h2, l2); split2(g6.w, g7.w, h3, l3);
    p = &XB[(dg + 96) * 128 + sq * 2];
    *(uint4v*)(p)     = (uint4v){h0, l0, h1, l1};
    *(uint4v*)(p + 4) = (uint4v){h2, l2, h3, l3};
  }

  // LDS writes visible to all waves; in-flight A loads NOT drained
  asm volatile("s_waitcnt lgkmcnt(0)" ::: "memory");
  __builtin_amdgcn_s_barrier();

  float16 acc0, acc1;
#pragma unroll
  for (int q = 0; q < 16; ++q) { acc0[q] = 0.0f; acc1[q] = 0.0f; }

  // software pipeline; every load group pinned with sched_barrier(0).
  // A loads are always in-bounds (buffer holds MAXCH slots); only the
  // MFMAs are predicated, so garbage never enters the accumulators.
  LOADA(qH0, qL0, 3) LOADA(qH1, qL1, 4) LOADA(qH2, qL2, 5)
  __builtin_amdgcn_sched_barrier(0);
  CHUNK(pH0, pL0, 0) CHUNK(pH1, pL1, 1) CHUNK(pH2, pL2, 2)

  LOADA(pH0, pL0, 6) LOADA(pH1, pL1, 7) LOADA(pH2, pL2, 8)
  __builtin_amdgcn_sched_barrier(0);
  CHUNK(qH0, qL0, 3) CHUNK(qH1, qL1, 4) CHUNK(qH2, qL2, 5)

  LOADA(qH0, qL0, 9) LOADA(qH1, qL1, 10) LOADA(qH2, qL2, 11)
  __builtin_amdgcn_sched_barrier(0);
  CHUNK(pH0, pL0, 6) CHUNK_P(pH1, pL1, 7) CHUNK_P(pH2, pL2, 8)

  CHUNK_P(qH0, qL0, 9) CHUNK_P(qH1, qL1, 10) CHUNK_P(qH2, qL2, 11)

  // epilogue: C/D map (32x32): col = lane&31, row = (r&3)+8*(r>>2)+4*half;
  // acc0 -> cols s0+m, acc1 -> cols s0+32+m.  NON-TEMPORAL stores: out is
  // never read on-device; keep it out of L2/L3 so x stays L3-resident and
  // the HBM bus runs a pure write stream.
  const int b  = tau / STILES_PER_B;
  const int s0 = (tau % STILES_PER_B) * STW;
  float* ob = out + (size_t)b * PER_B + (size_t)s0 + m;
#pragma unroll
  for (int r = 0; r < 16; ++r) {
    const int row = (r & 3) + 8 * (r >> 2) + 4 * half;
    float* orow = ob + (size_t)(c0 + row) * SPATIAL;
    __builtin_nontemporal_store(acc0[r], orow);
    __builtin_nontemporal_store(acc1[r], orow + 32);
  }
}

extern "C" void kernel_launch(void* const* d_in, const int* in_sizes, int n_in,
                              void* d_out, int out_size, void* d_ws, size_t ws_size,
                              hipStream_t stream) {
  const float* x = (const float*)d_in[0];  // (32, 256, 56, 56) fp32
  const float* w = (const float*)d_in[1];  // (15,) fp32
  const int* ms = (const int*)d_in[2];     // scalar int (10)
  float* out = (float*)d_out;              // (32, 256, 56, 56) fp32

  // workspace: 2 x 96 KB fragment buffers = 192 KB total (< 256 KB proven)
  unsigned short* AhF = (unsigned short*)d_ws;       // 8*12*64*8*2B = 96 KB
  unsigned short* AlF = AhF + 8 * MAXCH * 64 * 8;    // 96 KB

  build_M_kernel<<<NCH, NCH, 0, stream>>>(w, ms, AhF, AlF);
  apply_M_kernel<<<NTILES, 512, 0, stream>>>(x, AhF, AlF, out);
}